// Round 10
// baseline (210.584 us; speedup 1.0000x reference)
//
#include <hip/hip_runtime.h>

// 2-layer GCN collapsed to scalar per-node quantities (verified R2):
//   dis = 1/sqrt(deg+1);  y = x*dis;  t[d] = sum_{e->d} y[src]
//   s = dis*(t+y);  z = dis * sum_j relu(s*W1[j]+b1[j])*W2[j]
//   out[d] = dis[d]*(sum_{e->d} z[src] + z[d]) + b2
//
// R21: DIAGNOSTIC round. After 5 attribution-blind nulls (R16-R20 all
// 153-166us) the per-kernel breakdown is unknown: harness 44us poison-fills
// crowd the rocprof top-5. This round doubles every kernel's work honestly:
// part_k re-partitions into shadow gcur2/packedB2; each agg kernel re-runs
// its sweep into a second LDS acc2 and writes a never-read shadow output
// (real stores -> no DCE). Correct path is byte-identical R16 (best, 153.5).
// Readout: dur ~= 153.5 + T (T = true kernel sum); any kernel with true dur
// >22us crosses the 44us fill threshold and shows in top-5 WITH counters.
// Revert instrumentation next round and attack what the counters indict.

#define SB_BITS 9
#define SBK     512           // nodes per bucket
#define MAXB    256           // histogram size == TBP (1 bucket/thread)
#define TBP     256           // part_k block size
#define NAPB    1024          // part_k grid (64 blocks per set)
#define TPT     4096          // part_k tile (16 edges/thread)
#define KPT     16
#define NW      4             // waves per part_k block
#define NSET    16            // independent cursor/region sets
#define GSTRIDE 8             // u32 stride between cursors (32B granule)
#define TBA     1024          // aggregation block size (16 waves = 16 sets)

__device__ inline void lds_addf(float* p, float v) {
    __hip_atomic_fetch_add(p, v, __ATOMIC_RELAXED, __HIP_MEMORY_SCOPE_WORKGROUP);
}

// ---------------- K1: partition (x2 via shadow) ----------------
__global__ __launch_bounds__(TBP) void part_k(
        const int* __restrict__ src, const int* __restrict__ dst, int E,
        int cap, int capS, unsigned* __restrict__ gcur,
        unsigned* __restrict__ packedB, unsigned* __restrict__ gcur2,
        unsigned* __restrict__ packedB2) {
    __shared__ unsigned sp[TPT];
    __shared__ unsigned char sbk[TPT];
    __shared__ unsigned woff[NW][MAXB];
    __shared__ unsigned cnt2[NW][MAXB];
    __shared__ unsigned scn[MAXB];
    __shared__ unsigned gbase[MAXB];
    __shared__ unsigned wtot[NW];
    const int t = threadIdx.x;
    const int w = t >> 6;
    const int lane = t & 63;
    const int set = blockIdx.x & (NSET - 1);
    int CH = (E + (int)gridDim.x - 1) / (int)gridDim.x;
    int cs = blockIdx.x * CH;
    int ce = min(cs + CH, E);
    for (int rep = 0; rep < 2; rep++) {
        unsigned* GC = rep ? gcur2 : gcur;
        unsigned* PB = rep ? packedB2 : packedB;
        for (int ts = cs; ts < ce; ts += TPT) {
            int tcnt = min(TPT, ce - ts);
            #pragma unroll
            for (int ww = 0; ww < NW; ww++) { woff[ww][t] = 0u; cnt2[ww][t] = 0u; }
            __syncthreads();
            unsigned es[KPT], ed[KPT]; int nk = 0;
            #pragma unroll
            for (int k = 0; k < KPT; k++) {
                int j = ts + t + k * TBP;
                if (j < ce) {
                    es[k] = (unsigned)src[j];
                    ed[k] = (unsigned)dst[j];
                    atomicAdd(&woff[w][ed[k] >> SB_BITS], 1u);
                    nk = k + 1;
                }
            }
            __syncthreads();
            unsigned h0 = woff[0][t], h1 = woff[1][t], h2 = woff[2][t], h3 = woff[3][t];
            woff[0][t] = 0u; woff[1][t] = h0; woff[2][t] = h0 + h1;
            woff[3][t] = h0 + h1 + h2;
            unsigned th = h0 + h1 + h2 + h3;
            gbase[t] = th ? atomicAdd(&GC[(t * NSET + set) * GSTRIDE], th) : 0u;
            unsigned v = th;
            #pragma unroll
            for (int off = 1; off < 64; off <<= 1) {
                unsigned u = __shfl_up(v, off, 64);
                if (lane >= off) v += u;
            }
            if (lane == 63) wtot[w] = v;
            __syncthreads();
            unsigned wpre = 0;
            #pragma unroll
            for (int ww = 0; ww < NW; ww++) wpre += (ww < w) ? wtot[ww] : 0u;
            scn[t] = wpre + v - th;
            __syncthreads();
            for (int k = 0; k < nk; k++) {
                unsigned b = ed[k] >> SB_BITS;
                unsigned r = scn[b] + woff[w][b] + atomicAdd(&cnt2[w][b], 1u);
                sp[r]  = es[k] | ((ed[k] & (SBK - 1u)) << 17);
                sbk[r] = (unsigned char)b;
            }
            __syncthreads();
            #pragma unroll
            for (int k = 0; k < KPT; k++) {
                int j2 = t + k * TBP;
                if (j2 < tcnt) {
                    unsigned b = sbk[j2];
                    unsigned gpos = gbase[b] + (unsigned)j2 - scn[b];
                    if (gpos < (unsigned)capS)
                        PB[(size_t)b * cap + (size_t)set * capS + gpos] = sp[j2];
                }
            }
            __syncthreads();
        }
    }
}

// ---------------- K2: degree + prep1 (x2 via acc2/ysh) ----------------
__global__ __launch_bounds__(TBA) void degp_k(
        const unsigned* __restrict__ packedB, const unsigned* __restrict__ gcur,
        int cap, int capS, const float* __restrict__ x, int N,
        float* __restrict__ dis, float* __restrict__ y,
        float* __restrict__ ysh) {
    __shared__ unsigned acc[SBK];
    __shared__ unsigned acc2[SBK];
    if (threadIdx.x < SBK) { acc[threadIdx.x] = 0u; acc2[threadIdx.x] = 0u; }
    __syncthreads();
    const int b = blockIdx.x;
    const int w = threadIdx.x >> 6;      // wave = set
    const int lane = threadIdx.x & 63;
    unsigned cnt = min(gcur[(b * NSET + w) * GSTRIDE], (unsigned)capS);
    const unsigned* p = packedB + (size_t)b * cap + (size_t)w * capS;
    const uint4* p4 = (const uint4*)p;
    unsigned nq = cnt >> 2;
    unsigned qi = lane;
    for (; qi + 64 < nq; qi += 128) {
        uint4 a = p4[qi], c = p4[qi + 64];
        atomicAdd(&acc[a.x >> 17], 1u); atomicAdd(&acc[a.y >> 17], 1u);
        atomicAdd(&acc[a.z >> 17], 1u); atomicAdd(&acc[a.w >> 17], 1u);
        atomicAdd(&acc[c.x >> 17], 1u); atomicAdd(&acc[c.y >> 17], 1u);
        atomicAdd(&acc[c.z >> 17], 1u); atomicAdd(&acc[c.w >> 17], 1u);
    }
    for (; qi < nq; qi += 64) {
        uint4 a = p4[qi];
        atomicAdd(&acc[a.x >> 17], 1u); atomicAdd(&acc[a.y >> 17], 1u);
        atomicAdd(&acc[a.z >> 17], 1u); atomicAdd(&acc[a.w >> 17], 1u);
    }
    for (unsigned j = (nq << 2) + lane; j < cnt; j += 64)
        atomicAdd(&acc[p[j] >> 17], 1u);
    __syncthreads();
    const int base = b << SB_BITS;
    if (threadIdx.x < SBK) {
        int gi = base + threadIdx.x;
        if (gi < N) {
            float rr = 1.0f / sqrtf((float)(1u + acc[threadIdx.x]));  // +1 self loop
            dis[gi] = rr;
            y[gi] = x[gi] * rr;
        }
    }
    // ---- instrumentation: second full sweep into acc2, shadow output ----
    qi = lane;
    for (; qi + 64 < nq; qi += 128) {
        uint4 a = p4[qi], c = p4[qi + 64];
        atomicAdd(&acc2[a.x >> 17], 1u); atomicAdd(&acc2[a.y >> 17], 1u);
        atomicAdd(&acc2[a.z >> 17], 1u); atomicAdd(&acc2[a.w >> 17], 1u);
        atomicAdd(&acc2[c.x >> 17], 1u); atomicAdd(&acc2[c.y >> 17], 1u);
        atomicAdd(&acc2[c.z >> 17], 1u); atomicAdd(&acc2[c.w >> 17], 1u);
    }
    for (; qi < nq; qi += 64) {
        uint4 a = p4[qi];
        atomicAdd(&acc2[a.x >> 17], 1u); atomicAdd(&acc2[a.y >> 17], 1u);
        atomicAdd(&acc2[a.z >> 17], 1u); atomicAdd(&acc2[a.w >> 17], 1u);
    }
    for (unsigned j = (nq << 2) + lane; j < cnt; j += 64)
        atomicAdd(&acc2[p[j] >> 17], 1u);
    __syncthreads();
    if (threadIdx.x < SBK) {
        int gi = base + threadIdx.x;
        if (gi < N)
            ysh[gi] = x[gi] * (1.0f / sqrtf((float)(1u + acc2[threadIdx.x])));
    }
}

// ---------------- K3: gather y + prep2 (x2 via acc2/zsh) ----------------
__global__ __launch_bounds__(TBA) void gacc1_k(
        const unsigned* __restrict__ packedB, const unsigned* __restrict__ gcur,
        const float* __restrict__ val /* y */, int cap, int capS,
        const float* __restrict__ dis,
        const float* __restrict__ W1, const float* __restrict__ b1,
        const float* __restrict__ W2, float* __restrict__ z,
        float* __restrict__ zsh, int N) {
    __shared__ float acc[SBK];
    __shared__ float acc2[SBK];
    __shared__ float sW1[256], sb1[256], sW2[256];
    if (threadIdx.x < 256) {
        sW1[threadIdx.x] = W1[threadIdx.x];
        sb1[threadIdx.x] = b1[threadIdx.x];
        sW2[threadIdx.x] = W2[threadIdx.x];
    }
    if (threadIdx.x < SBK) { acc[threadIdx.x] = 0.0f; acc2[threadIdx.x] = 0.0f; }
    __syncthreads();
    const int b = blockIdx.x;
    const int w = threadIdx.x >> 6;
    const int lane = threadIdx.x & 63;
    unsigned cnt = min(gcur[(b * NSET + w) * GSTRIDE], (unsigned)capS);
    const unsigned* p = packedB + (size_t)b * cap + (size_t)w * capS;
    const uint4* p4 = (const uint4*)p;
    unsigned nq = cnt >> 2;
    unsigned qi = lane;
    for (; qi + 64 < nq; qi += 128) {
        uint4 a = p4[qi], c = p4[qi + 64];
        float v0 = val[a.x & 0x1FFFFu], v1 = val[a.y & 0x1FFFFu];
        float v2 = val[a.z & 0x1FFFFu], v3 = val[a.w & 0x1FFFFu];
        float v4 = val[c.x & 0x1FFFFu], v5 = val[c.y & 0x1FFFFu];
        float v6 = val[c.z & 0x1FFFFu], v7 = val[c.w & 0x1FFFFu];
        lds_addf(&acc[a.x >> 17], v0); lds_addf(&acc[a.y >> 17], v1);
        lds_addf(&acc[a.z >> 17], v2); lds_addf(&acc[a.w >> 17], v3);
        lds_addf(&acc[c.x >> 17], v4); lds_addf(&acc[c.y >> 17], v5);
        lds_addf(&acc[c.z >> 17], v6); lds_addf(&acc[c.w >> 17], v7);
    }
    for (; qi < nq; qi += 64) {
        uint4 a = p4[qi];
        float v0 = val[a.x & 0x1FFFFu], v1 = val[a.y & 0x1FFFFu];
        float v2 = val[a.z & 0x1FFFFu], v3 = val[a.w & 0x1FFFFu];
        lds_addf(&acc[a.x >> 17], v0); lds_addf(&acc[a.y >> 17], v1);
        lds_addf(&acc[a.z >> 17], v2); lds_addf(&acc[a.w >> 17], v3);
    }
    for (unsigned j = (nq << 2) + lane; j < cnt; j += 64) {
        unsigned pk = p[j];
        lds_addf(&acc[pk >> 17], val[pk & 0x1FFFFu]);
    }
    __syncthreads();
    const int base = b << SB_BITS;
    const float4* w1v = (const float4*)sW1;
    const float4* b1v = (const float4*)sb1;
    const float4* w2v = (const float4*)sW2;
    if (threadIdx.x < SBK) {
        int gi = base + threadIdx.x;
        if (gi < N) {
            float tt = acc[threadIdx.x];
            float rr = dis[gi];
            float s = rr * (tt + val[gi]);
            float g = 0.0f;
            #pragma unroll 8
            for (int jj = 0; jj < 64; jj++) {   // H=256 -> 64 quads
                float4 a = w1v[jj], bb = b1v[jj], c = w2v[jj];
                float h0 = fmaf(s, a.x, bb.x); h0 = h0 > 0.0f ? h0 : 0.0f;
                float h1 = fmaf(s, a.y, bb.y); h1 = h1 > 0.0f ? h1 : 0.0f;
                float h2 = fmaf(s, a.z, bb.z); h2 = h2 > 0.0f ? h2 : 0.0f;
                float h3 = fmaf(s, a.w, bb.w); h3 = h3 > 0.0f ? h3 : 0.0f;
                g = fmaf(h0, c.x, g); g = fmaf(h1, c.y, g);
                g = fmaf(h2, c.z, g); g = fmaf(h3, c.w, g);
            }
            z[gi] = g * rr;
        }
    }
    // ---- instrumentation: second full gather sweep into acc2, shadow out ----
    qi = lane;
    for (; qi + 64 < nq; qi += 128) {
        uint4 a = p4[qi], c = p4[qi + 64];
        float v0 = val[a.x & 0x1FFFFu], v1 = val[a.y & 0x1FFFFu];
        float v2 = val[a.z & 0x1FFFFu], v3 = val[a.w & 0x1FFFFu];
        float v4 = val[c.x & 0x1FFFFu], v5 = val[c.y & 0x1FFFFu];
        float v6 = val[c.z & 0x1FFFFu], v7 = val[c.w & 0x1FFFFu];
        lds_addf(&acc2[a.x >> 17], v0); lds_addf(&acc2[a.y >> 17], v1);
        lds_addf(&acc2[a.z >> 17], v2); lds_addf(&acc2[a.w >> 17], v3);
        lds_addf(&acc2[c.x >> 17], v4); lds_addf(&acc2[c.y >> 17], v5);
        lds_addf(&acc2[c.z >> 17], v6); lds_addf(&acc2[c.w >> 17], v7);
    }
    for (; qi < nq; qi += 64) {
        uint4 a = p4[qi];
        float v0 = val[a.x & 0x1FFFFu], v1 = val[a.y & 0x1FFFFu];
        float v2 = val[a.z & 0x1FFFFu], v3 = val[a.w & 0x1FFFFu];
        lds_addf(&acc2[a.x >> 17], v0); lds_addf(&acc2[a.y >> 17], v1);
        lds_addf(&acc2[a.z >> 17], v2); lds_addf(&acc2[a.w >> 17], v3);
    }
    for (unsigned j = (nq << 2) + lane; j < cnt; j += 64) {
        unsigned pk = p[j];
        lds_addf(&acc2[pk >> 17], val[pk & 0x1FFFFu]);
    }
    __syncthreads();
    if (threadIdx.x < SBK) {
        int gi = base + threadIdx.x;
        if (gi < N) zsh[gi] = acc2[threadIdx.x] * dis[gi];
    }
}

// ---------------- K4: gather z + finout (x2 via acc2/outsh) ----------------
__global__ __launch_bounds__(TBA) void gacc2_k(
        const unsigned* __restrict__ packedB, const unsigned* __restrict__ gcur,
        const float* __restrict__ val /* z */, int cap, int capS,
        const float* __restrict__ dis, const float* __restrict__ b2,
        float* __restrict__ out, float* __restrict__ outsh, int N) {
    __shared__ float acc[SBK];
    __shared__ float acc2[SBK];
    if (threadIdx.x < SBK) { acc[threadIdx.x] = 0.0f; acc2[threadIdx.x] = 0.0f; }
    __syncthreads();
    const int b = blockIdx.x;
    const int w = threadIdx.x >> 6;
    const int lane = threadIdx.x & 63;
    unsigned cnt = min(gcur[(b * NSET + w) * GSTRIDE], (unsigned)capS);
    const unsigned* p = packedB + (size_t)b * cap + (size_t)w * capS;
    const uint4* p4 = (const uint4*)p;
    unsigned nq = cnt >> 2;
    unsigned qi = lane;
    for (; qi + 64 < nq; qi += 128) {
        uint4 a = p4[qi], c = p4[qi + 64];
        float v0 = val[a.x & 0x1FFFFu], v1 = val[a.y & 0x1FFFFu];
        float v2 = val[a.z & 0x1FFFFu], v3 = val[a.w & 0x1FFFFu];
        float v4 = val[c.x & 0x1FFFFu], v5 = val[c.y & 0x1FFFFu];
        float v6 = val[c.z & 0x1FFFFu], v7 = val[c.w & 0x1FFFFu];
        lds_addf(&acc[a.x >> 17], v0); lds_addf(&acc[a.y >> 17], v1);
        lds_addf(&acc[a.z >> 17], v2); lds_addf(&acc[a.w >> 17], v3);
        lds_addf(&acc[c.x >> 17], v4); lds_addf(&acc[c.y >> 17], v5);
        lds_addf(&acc[c.z >> 17], v6); lds_addf(&acc[c.w >> 17], v7);
    }
    for (; qi < nq; qi += 64) {
        uint4 a = p4[qi];
        float v0 = val[a.x & 0x1FFFFu], v1 = val[a.y & 0x1FFFFu];
        float v2 = val[a.z & 0x1FFFFu], v3 = val[a.w & 0x1FFFFu];
        lds_addf(&acc[a.x >> 17], v0); lds_addf(&acc[a.y >> 17], v1);
        lds_addf(&acc[a.z >> 17], v2); lds_addf(&acc[a.w >> 17], v3);
    }
    for (unsigned j = (nq << 2) + lane; j < cnt; j += 64) {
        unsigned pk = p[j];
        lds_addf(&acc[pk >> 17], val[pk & 0x1FFFFu]);
    }
    __syncthreads();
    const int base = b << SB_BITS;
    float bb2 = b2[0];
    if (threadIdx.x < SBK) {
        int gi = base + threadIdx.x;
        if (gi < N) {
            out[gi] = dis[gi] * (acc[threadIdx.x] + val[gi]) + bb2;
        }
    }
    // ---- instrumentation: second full gather sweep into acc2, shadow out ----
    qi = lane;
    for (; qi + 64 < nq; qi += 128) {
        uint4 a = p4[qi], c = p4[qi + 64];
        float v0 = val[a.x & 0x1FFFFu], v1 = val[a.y & 0x1FFFFu];
        float v2 = val[a.z & 0x1FFFFu], v3 = val[a.w & 0x1FFFFu];
        float v4 = val[c.x & 0x1FFFFu], v5 = val[c.y & 0x1FFFFu];
        float v6 = val[c.z & 0x1FFFFu], v7 = val[c.w & 0x1FFFFu];
        lds_addf(&acc2[a.x >> 17], v0); lds_addf(&acc2[a.y >> 17], v1);
        lds_addf(&acc2[a.z >> 17], v2); lds_addf(&acc2[a.w >> 17], v3);
        lds_addf(&acc2[c.x >> 17], v4); lds_addf(&acc2[c.y >> 17], v5);
        lds_addf(&acc2[c.z >> 17], v6); lds_addf(&acc2[c.w >> 17], v7);
    }
    for (; qi < nq; qi += 64) {
        uint4 a = p4[qi];
        float v0 = val[a.x & 0x1FFFFu], v1 = val[a.y & 0x1FFFFu];
        float v2 = val[a.z & 0x1FFFFu], v3 = val[a.w & 0x1FFFFu];
        lds_addf(&acc2[a.x >> 17], v0); lds_addf(&acc2[a.y >> 17], v1);
        lds_addf(&acc2[a.z >> 17], v2); lds_addf(&acc2[a.w >> 17], v3);
    }
    for (unsigned j = (nq << 2) + lane; j < cnt; j += 64) {
        unsigned pk = p[j];
        lds_addf(&acc2[pk >> 17], val[pk & 0x1FFFFu]);
    }
    __syncthreads();
    if (threadIdx.x < SBK) {
        int gi = base + threadIdx.x;
        if (gi < N) outsh[gi] = acc2[threadIdx.x] + val[gi];
    }
}

extern "C" void kernel_launch(void* const* d_in, const int* in_sizes, int n_in,
                              void* d_out, int out_size, void* d_ws, size_t ws_size,
                              hipStream_t stream) {
    const float* x   = (const float*)d_in[0];
    const int*   ei  = (const int*)d_in[1];     // int32 (JAX x64-off)
    const float* W1  = (const float*)d_in[2];
    const float* b1  = (const float*)d_in[3];
    const float* W2  = (const float*)d_in[4];
    const float* b2  = (const float*)d_in[5];
    float*       out = (float*)d_out;

    const int N = in_sizes[0];        // 100000
    const int E = in_sizes[1] / 2;    // 3200000

    const int* srcp = ei;
    const int* dstp = ei + E;

    const int NB   = (N + SBK - 1) >> SB_BITS;            // 196
    const int capS = (E / (NB * NSET) + 384 + 7) & ~7;    // ~12 sigma slack
    const int cap  = capS * NSET;
    const int NCUR = NB * NSET * GSTRIDE;                 // 25088 u32

    // workspace (u32 units):
    // [gcur NCUR][gcur2 NCUR][dis N][y N][z N][ysh N][zsh N][outsh N]
    // [packedB NB*cap][packedB2 NB*cap]
    unsigned* W     = (unsigned*)d_ws;
    unsigned* gcur  = W;
    unsigned* gcur2 = W + (size_t)NCUR;
    float*    dis   = (float*)(W + (size_t)2 * NCUR);
    float*    y     = (float*)(W + (size_t)2 * NCUR + (size_t)N);
    float*    z     = (float*)(W + (size_t)2 * NCUR + (size_t)2 * N);
    float*    ysh   = (float*)(W + (size_t)2 * NCUR + (size_t)3 * N);
    float*    zsh   = (float*)(W + (size_t)2 * NCUR + (size_t)4 * N);
    float*    outsh = (float*)(W + (size_t)2 * NCUR + (size_t)5 * N);
    unsigned* packedB  = W + (size_t)2 * NCUR + (size_t)6 * N;
    unsigned* packedB2 = packedB + (size_t)NB * cap;

    hipMemsetAsync(gcur, 0, (size_t)2 * NCUR * sizeof(unsigned), stream);

    part_k <<<NAPB, TBP, 0, stream>>>(srcp, dstp, E, cap, capS, gcur, packedB,
                                      gcur2, packedB2);
    degp_k <<<NB, TBA, 0, stream>>>(packedB, gcur, cap, capS, x, N, dis, y, ysh);
    gacc1_k<<<NB, TBA, 0, stream>>>(packedB, gcur, y, cap, capS, dis,
                                    W1, b1, W2, z, zsh, N);
    gacc2_k<<<NB, TBA, 0, stream>>>(packedB, gcur, z, cap, capS, dis, b2,
                                    out, outsh, N);
}

// Round 11
// 174.612 us; speedup vs baseline: 1.2060x; 1.2060x over previous
//
#include <hip/hip_runtime.h>

// 2-layer GCN collapsed to scalar per-node quantities (verified R2):
//   dis = 1/sqrt(deg+1);  y = x*dis;  t[d] = sum_{e->d} y[src]
//   s = dis*(t+y);  z = dis * sum_j relu(s*W1[j]+b1[j])*W2[j]
//   out[d] = dis[d]*(sum_{e->d} z[src] + z[d]) + b2
//
// R22: ONE fused kernel. R21 diagnostic: true kernel sum ~57-70us vs 153.5
// measured -> ~90us is per-dispatch machinery (launch/drain + implicit
// per-dispatch L2 wb+inv across 8 XCDs + fill interleave). Fix: memset + one
// 196-block x 1024-thread kernel (co-resident, 1 block/CU) with 3 fence-free
// grid barriers (R14-proven: vmcnt-drained arrival + device-scope counter +
// agent-load spin). Coherence without fences: every cross-block array is
// write-ONCE via agent write-through stores, read in later phases with plain
// cached loads (dispatch-start acquire cleared poison; content never changes
// after its write phase -> no stale line is reachable). Gathers keep the L2
// path; packedB re-reads in ph3/4 become L2 hits (was 8.2MB HBM re-fetch).
// Agg bodies byte-equal to R16 (best measured).

#define SB_BITS 9
#define SBK     512           // nodes per bucket
#define MAXB    256           // histogram size (NB <= 256)
#define TBF     1024          // fused block size (16 waves)
#define KPT     4             // edges/thread/tile in partition phase
#define TPT     4096          // partition tile (TBF * KPT)
#define NWP     16            // histogram waves
#define NSET    16            // cursor/region sets
#define GSTRIDE 8             // u32 stride between cursors (32B granule)

__device__ inline unsigned agent_ld_u(const unsigned* p) {
    return __hip_atomic_load(p, __ATOMIC_RELAXED, __HIP_MEMORY_SCOPE_AGENT);
}
__device__ inline void agent_st_u(unsigned* p, unsigned v) {
    __hip_atomic_store(p, v, __ATOMIC_RELAXED, __HIP_MEMORY_SCOPE_AGENT);
}
__device__ inline void agent_st_f(float* p, float v) {
    __hip_atomic_store(p, v, __ATOMIC_RELAXED, __HIP_MEMORY_SCOPE_AGENT);
}
__device__ inline void lds_addf(float* p, float v) {
    __hip_atomic_fetch_add(p, v, __ATOMIC_RELAXED, __HIP_MEMORY_SCOPE_WORKGROUP);
}

// fence-free grid barrier: __syncthreads drains each wave's vmem (compiler
// emits s_waitcnt vmcnt(0) before s_barrier), so all agent write-throughs
// are at the coherent point before arrival. No cache maintenance needed.
__device__ inline void grid_bar(unsigned* c, int nblk) {
    __syncthreads();
    if (threadIdx.x == 0) {
        __hip_atomic_fetch_add(c, 1u, __ATOMIC_RELAXED, __HIP_MEMORY_SCOPE_AGENT);
        while (__hip_atomic_load(c, __ATOMIC_RELAXED, __HIP_MEMORY_SCOPE_AGENT)
               < (unsigned)nblk)
            __builtin_amdgcn_s_sleep(2);
    }
    __syncthreads();
}

__global__ __launch_bounds__(TBF) void fused_k(
        const int* __restrict__ src, const int* __restrict__ dst, int E,
        const float* __restrict__ x,
        const float* __restrict__ W1, const float* __restrict__ b1,
        const float* __restrict__ W2, const float* __restrict__ b2,
        int N, int NB, int cap, int capS,
        unsigned* gcur, unsigned* bar,
        float* dis, float* y, float* z,
        unsigned* packedB, float* __restrict__ out) {
    __shared__ unsigned sp[TPT];
    __shared__ unsigned char sbk[TPT];
    __shared__ unsigned woff[NWP][MAXB];
    __shared__ unsigned cnt2[NWP][MAXB];
    __shared__ unsigned scn[MAXB];
    __shared__ unsigned gbase[MAXB];
    __shared__ unsigned wtot[4];
    __shared__ unsigned accU[SBK];
    __shared__ float sW1[256], sb1[256], sW2[256];
    float* accF = (float*)accU;

    const int t = threadIdx.x;
    const int wv = t >> 6;
    const int lane = t & 63;
    const int blk = blockIdx.x;

    // ================= phase 1: partition =================
    {
        const int set = blk & (NSET - 1);
        int CH = (E + NB - 1) / NB;
        int cs = blk * CH;
        int ce = min(cs + CH, E);
        for (int ts = cs; ts < ce; ts += TPT) {
            int tcnt = min(TPT, ce - ts);
            for (int i = t; i < NWP * MAXB; i += TBF) {
                ((unsigned*)woff)[i] = 0u;
                ((unsigned*)cnt2)[i] = 0u;
            }
            __syncthreads();
            unsigned es[KPT], ed[KPT]; int nk = 0;
            #pragma unroll
            for (int k = 0; k < KPT; k++) {
                int j = ts + t + k * TBF;
                if (j < ce) {
                    es[k] = (unsigned)src[j];
                    ed[k] = (unsigned)dst[j];
                    atomicAdd(&woff[wv][ed[k] >> SB_BITS], 1u);
                    nk = k + 1;
                }
            }
            __syncthreads();
            unsigned th = 0u, v = 0u;
            if (t < MAXB) {
                #pragma unroll
                for (int ww = 0; ww < NWP; ww++) {
                    unsigned hh = woff[ww][t];
                    woff[ww][t] = th;      // exclusive per-wave offset
                    th += hh;
                }
                gbase[t] = th ? atomicAdd(&gcur[(t * NSET + set) * GSTRIDE], th) : 0u;
                v = th;
                #pragma unroll
                for (int off = 1; off < 64; off <<= 1) {
                    unsigned u = __shfl_up(v, off, 64);
                    if (lane >= off) v += u;
                }
                if (lane == 63) wtot[t >> 6] = v;
            }
            __syncthreads();
            if (t < MAXB) {
                unsigned wpre = 0;
                #pragma unroll
                for (int ww = 0; ww < 4; ww++) wpre += (ww < (t >> 6)) ? wtot[ww] : 0u;
                scn[t] = wpre + v - th;    // block-exclusive base for bucket t
            }
            __syncthreads();
            for (int k = 0; k < nk; k++) {
                unsigned b = ed[k] >> SB_BITS;
                unsigned r = scn[b] + woff[wv][b] + atomicAdd(&cnt2[wv][b], 1u);
                sp[r]  = es[k] | ((ed[k] & (SBK - 1u)) << 17);
                sbk[r] = (unsigned char)b;
            }
            __syncthreads();
            #pragma unroll
            for (int k = 0; k < KPT; k++) {
                int j2 = t + k * TBF;
                if (j2 < tcnt) {
                    unsigned b = sbk[j2];
                    unsigned gpos = gbase[b] + (unsigned)j2 - scn[b];
                    if (gpos < (unsigned)capS)
                        agent_st_u(&packedB[(size_t)b * cap + (size_t)set * capS + gpos],
                                   sp[j2]);
                }
            }
            __syncthreads();
        }
    }
    grid_bar(bar, NB);

    // ================= phase 2: degree + prep1 =================
    if (t < SBK) accU[t] = 0u;
    __syncthreads();
    {
        unsigned cnt = min(agent_ld_u(&gcur[(blk * NSET + wv) * GSTRIDE]),
                           (unsigned)capS);
        const unsigned* p = packedB + (size_t)blk * cap + (size_t)wv * capS;
        const uint4* p4 = (const uint4*)p;
        unsigned nq = cnt >> 2;
        unsigned qi = lane;
        for (; qi + 64 < nq; qi += 128) {
            uint4 a = p4[qi], c = p4[qi + 64];
            atomicAdd(&accU[a.x >> 17], 1u); atomicAdd(&accU[a.y >> 17], 1u);
            atomicAdd(&accU[a.z >> 17], 1u); atomicAdd(&accU[a.w >> 17], 1u);
            atomicAdd(&accU[c.x >> 17], 1u); atomicAdd(&accU[c.y >> 17], 1u);
            atomicAdd(&accU[c.z >> 17], 1u); atomicAdd(&accU[c.w >> 17], 1u);
        }
        for (; qi < nq; qi += 64) {
            uint4 a = p4[qi];
            atomicAdd(&accU[a.x >> 17], 1u); atomicAdd(&accU[a.y >> 17], 1u);
            atomicAdd(&accU[a.z >> 17], 1u); atomicAdd(&accU[a.w >> 17], 1u);
        }
        for (unsigned j = (nq << 2) + lane; j < cnt; j += 64)
            atomicAdd(&accU[p[j] >> 17], 1u);
    }
    __syncthreads();
    if (t < SBK) {
        int gi = (blk << SB_BITS) + t;
        if (gi < N) {
            float rr = 1.0f / sqrtf((float)(1u + accU[t]));   // +1 self loop
            agent_st_f(&dis[gi], rr);
            agent_st_f(&y[gi], x[gi] * rr);
        }
    }
    grid_bar(bar + GSTRIDE, NB);

    // ================= phase 3: gather y + prep2 =================
    if (t < 256) { sW1[t] = W1[t]; sb1[t] = b1[t]; sW2[t] = W2[t]; }
    if (t < SBK) accF[t] = 0.0f;
    __syncthreads();
    {
        unsigned cnt = min(agent_ld_u(&gcur[(blk * NSET + wv) * GSTRIDE]),
                           (unsigned)capS);
        const unsigned* p = packedB + (size_t)blk * cap + (size_t)wv * capS;
        const uint4* p4 = (const uint4*)p;
        unsigned nq = cnt >> 2;
        unsigned qi = lane;
        for (; qi + 64 < nq; qi += 128) {
            uint4 a = p4[qi], c = p4[qi + 64];
            float v0 = y[a.x & 0x1FFFFu], v1 = y[a.y & 0x1FFFFu];
            float v2 = y[a.z & 0x1FFFFu], v3 = y[a.w & 0x1FFFFu];
            float v4 = y[c.x & 0x1FFFFu], v5 = y[c.y & 0x1FFFFu];
            float v6 = y[c.z & 0x1FFFFu], v7 = y[c.w & 0x1FFFFu];
            lds_addf(&accF[a.x >> 17], v0); lds_addf(&accF[a.y >> 17], v1);
            lds_addf(&accF[a.z >> 17], v2); lds_addf(&accF[a.w >> 17], v3);
            lds_addf(&accF[c.x >> 17], v4); lds_addf(&accF[c.y >> 17], v5);
            lds_addf(&accF[c.z >> 17], v6); lds_addf(&accF[c.w >> 17], v7);
        }
        for (; qi < nq; qi += 64) {
            uint4 a = p4[qi];
            float v0 = y[a.x & 0x1FFFFu], v1 = y[a.y & 0x1FFFFu];
            float v2 = y[a.z & 0x1FFFFu], v3 = y[a.w & 0x1FFFFu];
            lds_addf(&accF[a.x >> 17], v0); lds_addf(&accF[a.y >> 17], v1);
            lds_addf(&accF[a.z >> 17], v2); lds_addf(&accF[a.w >> 17], v3);
        }
        for (unsigned j = (nq << 2) + lane; j < cnt; j += 64) {
            unsigned pk = p[j];
            lds_addf(&accF[pk >> 17], y[pk & 0x1FFFFu]);
        }
    }
    __syncthreads();
    if (t < SBK) {
        int gi = (blk << SB_BITS) + t;
        if (gi < N) {
            float tt = accF[t];
            float rr = dis[gi];
            float s = rr * (tt + y[gi]);
            float g = 0.0f;
            const float4* w1v = (const float4*)sW1;
            const float4* b1v = (const float4*)sb1;
            const float4* w2v = (const float4*)sW2;
            #pragma unroll 8
            for (int jj = 0; jj < 64; jj++) {   // H=256 -> 64 quads
                float4 a = w1v[jj], bb = b1v[jj], c = w2v[jj];
                float h0 = fmaf(s, a.x, bb.x); h0 = h0 > 0.0f ? h0 : 0.0f;
                float h1 = fmaf(s, a.y, bb.y); h1 = h1 > 0.0f ? h1 : 0.0f;
                float h2 = fmaf(s, a.z, bb.z); h2 = h2 > 0.0f ? h2 : 0.0f;
                float h3 = fmaf(s, a.w, bb.w); h3 = h3 > 0.0f ? h3 : 0.0f;
                g = fmaf(h0, c.x, g); g = fmaf(h1, c.y, g);
                g = fmaf(h2, c.z, g); g = fmaf(h3, c.w, g);
            }
            agent_st_f(&z[gi], g * rr);
        }
    }
    grid_bar(bar + 2 * GSTRIDE, NB);

    // ================= phase 4: gather z + finout =================
    if (t < SBK) accF[t] = 0.0f;
    __syncthreads();
    {
        unsigned cnt = min(agent_ld_u(&gcur[(blk * NSET + wv) * GSTRIDE]),
                           (unsigned)capS);
        const unsigned* p = packedB + (size_t)blk * cap + (size_t)wv * capS;
        const uint4* p4 = (const uint4*)p;
        unsigned nq = cnt >> 2;
        unsigned qi = lane;
        for (; qi + 64 < nq; qi += 128) {
            uint4 a = p4[qi], c = p4[qi + 64];
            float v0 = z[a.x & 0x1FFFFu], v1 = z[a.y & 0x1FFFFu];
            float v2 = z[a.z & 0x1FFFFu], v3 = z[a.w & 0x1FFFFu];
            float v4 = z[c.x & 0x1FFFFu], v5 = z[c.y & 0x1FFFFu];
            float v6 = z[c.z & 0x1FFFFu], v7 = z[c.w & 0x1FFFFu];
            lds_addf(&accF[a.x >> 17], v0); lds_addf(&accF[a.y >> 17], v1);
            lds_addf(&accF[a.z >> 17], v2); lds_addf(&accF[a.w >> 17], v3);
            lds_addf(&accF[c.x >> 17], v4); lds_addf(&accF[c.y >> 17], v5);
            lds_addf(&accF[c.z >> 17], v6); lds_addf(&accF[c.w >> 17], v7);
        }
        for (; qi < nq; qi += 64) {
            uint4 a = p4[qi];
            float v0 = z[a.x & 0x1FFFFu], v1 = z[a.y & 0x1FFFFu];
            float v2 = z[a.z & 0x1FFFFu], v3 = z[a.w & 0x1FFFFu];
            lds_addf(&accF[a.x >> 17], v0); lds_addf(&accF[a.y >> 17], v1);
            lds_addf(&accF[a.z >> 17], v2); lds_addf(&accF[a.w >> 17], v3);
        }
        for (unsigned j = (nq << 2) + lane; j < cnt; j += 64) {
            unsigned pk = p[j];
            lds_addf(&accF[pk >> 17], z[pk & 0x1FFFFu]);
        }
    }
    __syncthreads();
    if (t < SBK) {
        int gi = (blk << SB_BITS) + t;
        if (gi < N)
            out[gi] = dis[gi] * (accF[t] + z[gi]) + b2[0];
    }
}

extern "C" void kernel_launch(void* const* d_in, const int* in_sizes, int n_in,
                              void* d_out, int out_size, void* d_ws, size_t ws_size,
                              hipStream_t stream) {
    const float* x   = (const float*)d_in[0];
    const int*   ei  = (const int*)d_in[1];     // int32 (JAX x64-off)
    const float* W1  = (const float*)d_in[2];
    const float* b1  = (const float*)d_in[3];
    const float* W2  = (const float*)d_in[4];
    const float* b2  = (const float*)d_in[5];
    float*       out = (float*)d_out;

    const int N = in_sizes[0];        // 100000
    const int E = in_sizes[1] / 2;    // 3200000

    const int* srcp = ei;
    const int* dstp = ei + E;

    const int NB   = (N + SBK - 1) >> SB_BITS;            // 196 (<= 256 CUs)
    const int capS = (E / (NB * NSET) + 384 + 7) & ~7;    // slack over ~1082 mean
    const int cap  = capS * NSET;
    const int NCUR = MAXB * NSET * GSTRIDE;               // 32768 u32

    // workspace (u32 units), zero-init prefix [gcur NCUR][bar 64]:
    // then [dis N][y N][z N][packedB NB*cap]
    unsigned* W    = (unsigned*)d_ws;
    unsigned* gcur = W;
    unsigned* bar  = W + (size_t)NCUR;                    // 3 barriers x GSTRIDE
    float*    dis  = (float*)(W + (size_t)NCUR + 64);
    float*    y    = (float*)(W + (size_t)NCUR + 64 + (size_t)N);
    float*    z    = (float*)(W + (size_t)NCUR + 64 + (size_t)2 * N);
    unsigned* packedB = W + (size_t)NCUR + 64 + (size_t)3 * N;

    hipMemsetAsync(gcur, 0, ((size_t)NCUR + 64) * sizeof(unsigned), stream);

    fused_k<<<NB, TBF, 0, stream>>>(srcp, dstp, E, x, W1, b1, W2, b2,
                                    N, NB, cap, capS, gcur, bar,
                                    dis, y, z, packedB, out);
}

// Round 12
// 160.888 us; speedup vs baseline: 1.3089x; 1.0853x over previous
//
#include <hip/hip_runtime.h>

// 2-layer GCN collapsed to scalar per-node quantities (verified R2):
//   dis = 1/sqrt(deg+1);  y = x*dis;  t[d] = sum_{e->d} y[src]
//   s = dis*(t+y);  z = dis * sum_j relu(s*W1[j]+b1[j])*W2[j]
//   out[d] = dis[d]*(sum_{e->d} z[src] + z[d]) + b2
//
// R23: 3 dispatches. Cost model fitted over R16/R21/R22:
//   total ~= kernels + ~44us (harness fill) + ~10us/dispatch.
// R22's full fusion lost 50us in the partition phase (196x1024 config + 3.2M
// scattered 4B write-through stores for packedB). R23: part_k reverts to its
// fast R16 form (1024x256, plain cached stores; the KERNEL BOUNDARY gives
// packedB/gcur coherence). Phases 2-4 stay fused (fused_agg, 196x1024, two
// R22-proven fence-free grid barriers). Cross-block data inside fused_agg is
// only dis/y/z (1.2MB agent write-through — trivial), read plainly after the
// barrier (R22's verified coherence argument). packedB stays L2-hot across
// all 3 agg phases. Agg bodies byte-equal to R16.

#define SB_BITS 9
#define SBK     512           // nodes per bucket
#define MAXB    256           // histogram size == TBP (1 bucket/thread)
#define TBP     256           // part_k block size
#define NAPB    1024          // part_k grid (64 blocks per set)
#define TPT     4096          // part_k tile (16 edges/thread)
#define KPT     16
#define NW      4             // waves per part_k block
#define NSET    16            // independent cursor/region sets
#define GSTRIDE 8             // u32 stride between cursors (32B granule)
#define TBA     1024          // fused_agg block size (16 waves = 16 sets)

__device__ inline void lds_addf(float* p, float v) {
    __hip_atomic_fetch_add(p, v, __ATOMIC_RELAXED, __HIP_MEMORY_SCOPE_WORKGROUP);
}
__device__ inline void agent_st_f(float* p, float v) {
    __hip_atomic_store(p, v, __ATOMIC_RELAXED, __HIP_MEMORY_SCOPE_AGENT);
}

// fence-free grid barrier (R22-proven): __syncthreads drains each wave's
// vmem (compiler emits s_waitcnt vmcnt(0) before s_barrier), so all agent
// write-throughs are globally performed before arrival. No cache maintenance.
__device__ inline void grid_bar(unsigned* c, int nblk) {
    __syncthreads();
    if (threadIdx.x == 0) {
        __hip_atomic_fetch_add(c, 1u, __ATOMIC_RELAXED, __HIP_MEMORY_SCOPE_AGENT);
        while (__hip_atomic_load(c, __ATOMIC_RELAXED, __HIP_MEMORY_SCOPE_AGENT)
               < (unsigned)nblk)
            __builtin_amdgcn_s_sleep(2);
    }
    __syncthreads();
}

// ---------------- K1: partition (R16 form, plain cached stores) ----------------
__global__ __launch_bounds__(TBP) void part_k(
        const int* __restrict__ src, const int* __restrict__ dst, int E,
        int cap, int capS, unsigned* __restrict__ gcur,
        unsigned* __restrict__ packedB) {
    __shared__ unsigned sp[TPT];
    __shared__ unsigned char sbk[TPT];
    __shared__ unsigned woff[NW][MAXB];
    __shared__ unsigned cnt2[NW][MAXB];
    __shared__ unsigned scn[MAXB];
    __shared__ unsigned gbase[MAXB];
    __shared__ unsigned wtot[NW];
    const int t = threadIdx.x;
    const int w = t >> 6;
    const int lane = t & 63;
    const int set = blockIdx.x & (NSET - 1);
    int CH = (E + (int)gridDim.x - 1) / (int)gridDim.x;
    int cs = blockIdx.x * CH;
    int ce = min(cs + CH, E);
    for (int ts = cs; ts < ce; ts += TPT) {
        int tcnt = min(TPT, ce - ts);
        #pragma unroll
        for (int ww = 0; ww < NW; ww++) { woff[ww][t] = 0u; cnt2[ww][t] = 0u; }
        __syncthreads();
        unsigned es[KPT], ed[KPT]; int nk = 0;
        #pragma unroll
        for (int k = 0; k < KPT; k++) {
            int j = ts + t + k * TBP;
            if (j < ce) {
                es[k] = (unsigned)src[j];
                ed[k] = (unsigned)dst[j];
                atomicAdd(&woff[w][ed[k] >> SB_BITS], 1u);
                nk = k + 1;
            }
        }
        __syncthreads();
        unsigned h0 = woff[0][t], h1 = woff[1][t], h2 = woff[2][t], h3 = woff[3][t];
        woff[0][t] = 0u; woff[1][t] = h0; woff[2][t] = h0 + h1;
        woff[3][t] = h0 + h1 + h2;
        unsigned th = h0 + h1 + h2 + h3;
        gbase[t] = th ? atomicAdd(&gcur[(t * NSET + set) * GSTRIDE], th) : 0u;
        unsigned v = th;
        #pragma unroll
        for (int off = 1; off < 64; off <<= 1) {
            unsigned u = __shfl_up(v, off, 64);
            if (lane >= off) v += u;
        }
        if (lane == 63) wtot[w] = v;
        __syncthreads();
        unsigned wpre = 0;
        #pragma unroll
        for (int ww = 0; ww < NW; ww++) wpre += (ww < w) ? wtot[ww] : 0u;
        scn[t] = wpre + v - th;        // block-exclusive base for bucket t
        __syncthreads();
        for (int k = 0; k < nk; k++) {
            unsigned b = ed[k] >> SB_BITS;
            unsigned r = scn[b] + woff[w][b] + atomicAdd(&cnt2[w][b], 1u);
            sp[r]  = es[k] | ((ed[k] & (SBK - 1u)) << 17);
            sbk[r] = (unsigned char)b;
        }
        __syncthreads();
        #pragma unroll
        for (int k = 0; k < KPT; k++) {
            int j2 = t + k * TBP;
            if (j2 < tcnt) {
                unsigned b = sbk[j2];
                unsigned gpos = gbase[b] + (unsigned)j2 - scn[b];
                if (gpos < (unsigned)capS)
                    packedB[(size_t)b * cap + (size_t)set * capS + gpos] = sp[j2];
            }
        }
        __syncthreads();
    }
}

// ---------------- K2: fused aggregation (phases 2-4, 2 grid barriers) ----------
__global__ __launch_bounds__(TBA) void fused_agg(
        const unsigned* __restrict__ packedB, const unsigned* __restrict__ gcur,
        int cap, int capS, int NB, unsigned* bar,
        const float* __restrict__ x,
        const float* __restrict__ W1, const float* __restrict__ b1,
        const float* __restrict__ W2, const float* __restrict__ b2,
        float* dis, float* y, float* z, float* __restrict__ out, int N) {
    __shared__ unsigned accU[SBK];
    __shared__ float sW1[256], sb1[256], sW2[256];
    float* accF = (float*)accU;
    const int t = threadIdx.x;
    const int wv = t >> 6;               // wave = set
    const int lane = t & 63;
    const int blk = blockIdx.x;
    const int base = blk << SB_BITS;

    const unsigned cnt = min(gcur[(blk * NSET + wv) * GSTRIDE], (unsigned)capS);
    const unsigned* p = packedB + (size_t)blk * cap + (size_t)wv * capS;
    const uint4* p4 = (const uint4*)p;
    const unsigned nq = cnt >> 2;

    // ===== phase 2: degree + prep1 =====
    if (t < SBK) accU[t] = 0u;
    __syncthreads();
    {
        unsigned qi = lane;
        for (; qi + 64 < nq; qi += 128) {
            uint4 a = p4[qi], c = p4[qi + 64];
            atomicAdd(&accU[a.x >> 17], 1u); atomicAdd(&accU[a.y >> 17], 1u);
            atomicAdd(&accU[a.z >> 17], 1u); atomicAdd(&accU[a.w >> 17], 1u);
            atomicAdd(&accU[c.x >> 17], 1u); atomicAdd(&accU[c.y >> 17], 1u);
            atomicAdd(&accU[c.z >> 17], 1u); atomicAdd(&accU[c.w >> 17], 1u);
        }
        for (; qi < nq; qi += 64) {
            uint4 a = p4[qi];
            atomicAdd(&accU[a.x >> 17], 1u); atomicAdd(&accU[a.y >> 17], 1u);
            atomicAdd(&accU[a.z >> 17], 1u); atomicAdd(&accU[a.w >> 17], 1u);
        }
        for (unsigned j = (nq << 2) + lane; j < cnt; j += 64)
            atomicAdd(&accU[p[j] >> 17], 1u);
    }
    __syncthreads();
    if (t < SBK) {
        int gi = base + t;
        if (gi < N) {
            float rr = 1.0f / sqrtf((float)(1u + accU[t]));   // +1 self loop
            agent_st_f(&dis[gi], rr);
            agent_st_f(&y[gi], x[gi] * rr);
        }
    }
    grid_bar(bar, NB);

    // ===== phase 3: gather y + prep2 =====
    if (t < 256) { sW1[t] = W1[t]; sb1[t] = b1[t]; sW2[t] = W2[t]; }
    __syncthreads();              // accU reuse: all reads of accU done above
    if (t < SBK) accF[t] = 0.0f;
    __syncthreads();
    {
        unsigned qi = lane;
        for (; qi + 64 < nq; qi += 128) {
            uint4 a = p4[qi], c = p4[qi + 64];
            float v0 = y[a.x & 0x1FFFFu], v1 = y[a.y & 0x1FFFFu];
            float v2 = y[a.z & 0x1FFFFu], v3 = y[a.w & 0x1FFFFu];
            float v4 = y[c.x & 0x1FFFFu], v5 = y[c.y & 0x1FFFFu];
            float v6 = y[c.z & 0x1FFFFu], v7 = y[c.w & 0x1FFFFu];
            lds_addf(&accF[a.x >> 17], v0); lds_addf(&accF[a.y >> 17], v1);
            lds_addf(&accF[a.z >> 17], v2); lds_addf(&accF[a.w >> 17], v3);
            lds_addf(&accF[c.x >> 17], v4); lds_addf(&accF[c.y >> 17], v5);
            lds_addf(&accF[c.z >> 17], v6); lds_addf(&accF[c.w >> 17], v7);
        }
        for (; qi < nq; qi += 64) {
            uint4 a = p4[qi];
            float v0 = y[a.x & 0x1FFFFu], v1 = y[a.y & 0x1FFFFu];
            float v2 = y[a.z & 0x1FFFFu], v3 = y[a.w & 0x1FFFFu];
            lds_addf(&accF[a.x >> 17], v0); lds_addf(&accF[a.y >> 17], v1);
            lds_addf(&accF[a.z >> 17], v2); lds_addf(&accF[a.w >> 17], v3);
        }
        for (unsigned j = (nq << 2) + lane; j < cnt; j += 64) {
            unsigned pk = p[j];
            lds_addf(&accF[pk >> 17], y[pk & 0x1FFFFu]);
        }
    }
    __syncthreads();
    if (t < SBK) {
        int gi = base + t;
        if (gi < N) {
            float tt = accF[t];
            float rr = dis[gi];
            float s = rr * (tt + y[gi]);
            float g = 0.0f;
            const float4* w1v = (const float4*)sW1;
            const float4* b1v = (const float4*)sb1;
            const float4* w2v = (const float4*)sW2;
            #pragma unroll 8
            for (int jj = 0; jj < 64; jj++) {   // H=256 -> 64 quads
                float4 a = w1v[jj], bb = b1v[jj], c = w2v[jj];
                float h0 = fmaf(s, a.x, bb.x); h0 = h0 > 0.0f ? h0 : 0.0f;
                float h1 = fmaf(s, a.y, bb.y); h1 = h1 > 0.0f ? h1 : 0.0f;
                float h2 = fmaf(s, a.z, bb.z); h2 = h2 > 0.0f ? h2 : 0.0f;
                float h3 = fmaf(s, a.w, bb.w); h3 = h3 > 0.0f ? h3 : 0.0f;
                g = fmaf(h0, c.x, g); g = fmaf(h1, c.y, g);
                g = fmaf(h2, c.z, g); g = fmaf(h3, c.w, g);
            }
            agent_st_f(&z[gi], g * rr);
        }
    }
    grid_bar(bar + GSTRIDE, NB);

    // ===== phase 4: gather z + finout =====
    if (t < SBK) accF[t] = 0.0f;
    __syncthreads();
    {
        unsigned qi = lane;
        for (; qi + 64 < nq; qi += 128) {
            uint4 a = p4[qi], c = p4[qi + 64];
            float v0 = z[a.x & 0x1FFFFu], v1 = z[a.y & 0x1FFFFu];
            float v2 = z[a.z & 0x1FFFFu], v3 = z[a.w & 0x1FFFFu];
            float v4 = z[c.x & 0x1FFFFu], v5 = z[c.y & 0x1FFFFu];
            float v6 = z[c.z & 0x1FFFFu], v7 = z[c.w & 0x1FFFFu];
            lds_addf(&accF[a.x >> 17], v0); lds_addf(&accF[a.y >> 17], v1);
            lds_addf(&accF[a.z >> 17], v2); lds_addf(&accF[a.w >> 17], v3);
            lds_addf(&accF[c.x >> 17], v4); lds_addf(&accF[c.y >> 17], v5);
            lds_addf(&accF[c.z >> 17], v6); lds_addf(&accF[c.w >> 17], v7);
        }
        for (; qi < nq; qi += 64) {
            uint4 a = p4[qi];
            float v0 = z[a.x & 0x1FFFFu], v1 = z[a.y & 0x1FFFFu];
            float v2 = z[a.z & 0x1FFFFu], v3 = z[a.w & 0x1FFFFu];
            lds_addf(&accF[a.x >> 17], v0); lds_addf(&accF[a.y >> 17], v1);
            lds_addf(&accF[a.z >> 17], v2); lds_addf(&accF[a.w >> 17], v3);
        }
        for (unsigned j = (nq << 2) + lane; j < cnt; j += 64) {
            unsigned pk = p[j];
            lds_addf(&accF[pk >> 17], z[pk & 0x1FFFFu]);
        }
    }
    __syncthreads();
    if (t < SBK) {
        int gi = base + t;
        if (gi < N)
            out[gi] = dis[gi] * (accF[t] + z[gi]) + b2[0];
    }
}

extern "C" void kernel_launch(void* const* d_in, const int* in_sizes, int n_in,
                              void* d_out, int out_size, void* d_ws, size_t ws_size,
                              hipStream_t stream) {
    const float* x   = (const float*)d_in[0];
    const int*   ei  = (const int*)d_in[1];     // int32 (JAX x64-off)
    const float* W1  = (const float*)d_in[2];
    const float* b1  = (const float*)d_in[3];
    const float* W2  = (const float*)d_in[4];
    const float* b2  = (const float*)d_in[5];
    float*       out = (float*)d_out;

    const int N = in_sizes[0];        // 100000
    const int E = in_sizes[1] / 2;    // 3200000

    const int* srcp = ei;
    const int* dstp = ei + E;

    const int NB   = (N + SBK - 1) >> SB_BITS;            // 196 (<= 256 CUs)
    const int capS = (E / (NB * NSET) + 384 + 7) & ~7;    // ~12 sigma slack
    const int cap  = capS * NSET;
    const int NCUR = MAXB * NSET * GSTRIDE;               // 32768 u32

    // workspace (u32 units), zero-init prefix [gcur NCUR][bar 64]:
    // then [dis N][y N][z N][packedB NB*cap]
    unsigned* W    = (unsigned*)d_ws;
    unsigned* gcur = W;
    unsigned* bar  = W + (size_t)NCUR;                    // 2 barriers x GSTRIDE
    float*    dis  = (float*)(W + (size_t)NCUR + 64);
    float*    y    = (float*)(W + (size_t)NCUR + 64 + (size_t)N);
    float*    z    = (float*)(W + (size_t)NCUR + 64 + (size_t)2 * N);
    unsigned* packedB = W + (size_t)NCUR + 64 + (size_t)3 * N;

    hipMemsetAsync(gcur, 0, ((size_t)NCUR + 64) * sizeof(unsigned), stream);

    part_k  <<<NAPB, TBP, 0, stream>>>(srcp, dstp, E, cap, capS, gcur, packedB);
    fused_agg<<<NB, TBA, 0, stream>>>(packedB, gcur, cap, capS, NB, bar,
                                      x, W1, b1, W2, b2, dis, y, z, out, N);
}

// Round 13
// 153.170 us; speedup vs baseline: 1.3748x; 1.0504x over previous
//
#include <hip/hip_runtime.h>

// 2-layer GCN collapsed to scalar per-node quantities (verified R2):
//   dis = 1/sqrt(deg+1);  y = x*dis;  t[d] = sum_{e->d} y[src]
//   s = dis*(t+y);  z = dis * sum_j relu(s*W1[j]+b1[j])*W2[j]
//   out[d] = dis[d]*(sum_{e->d} z[src] + z[d]) + b2
//
// R24: restore best-measured kernel = R16 (153.5us), byte-identical.
// Session ledger (R21 diagnostic + R22/R23 direct measurements):
//   ~44us harness poison-fill (fixed) + part_k ~20-25 + degree ~15 +
//   2x gather ~26 each (probe-rate bound: 3.2M scattered L1 probes + 3.2M
//   LDS atomics/pass) + ~15-30us dispatch machinery.
// Six mechanisms tested null on the gathers: more waves (R16 got +9 only),
// more CUs (R17 -7), issue depth (R19b ~0), L1-window reorder (R20 ~0),
// full fusion (R22 -21), agg fusion (R23 -7). Line-granularity src-sort
// prices out negative (sort walks cost ~2 degree-passes to cut probes 2.8x
// at 0.17 edges/node density). This is the structural floor of the approach.

#define SB_BITS 9
#define SBK     512           // nodes per bucket
#define MAXB    256           // histogram size == TBP (1 bucket/thread)
#define TBP     256           // part_k block size
#define NAPB    1024          // part_k grid (64 blocks per set)
#define TPT     4096          // part_k tile (16 edges/thread)
#define KPT     16
#define NW      4             // waves per part_k block
#define NSET    16            // independent cursor/region sets
#define GSTRIDE 8             // u32 stride between cursors (32B granule)
#define TBA     1024          // aggregation block size (16 waves = 16 sets)

__device__ inline void lds_addf(float* p, float v) {
    __hip_atomic_fetch_add(p, v, __ATOMIC_RELAXED, __HIP_MEMORY_SCOPE_WORKGROUP);
}

// ---------------- K1: partition ----------------
__global__ __launch_bounds__(TBP) void part_k(
        const int* __restrict__ src, const int* __restrict__ dst, int E,
        int cap, int capS, unsigned* __restrict__ gcur,
        unsigned* __restrict__ packedB) {
    __shared__ unsigned sp[TPT];
    __shared__ unsigned char sbk[TPT];
    __shared__ unsigned woff[NW][MAXB];
    __shared__ unsigned cnt2[NW][MAXB];
    __shared__ unsigned scn[MAXB];
    __shared__ unsigned gbase[MAXB];
    __shared__ unsigned wtot[NW];
    const int t = threadIdx.x;
    const int w = t >> 6;
    const int lane = t & 63;
    const int set = blockIdx.x & (NSET - 1);
    int CH = (E + (int)gridDim.x - 1) / (int)gridDim.x;
    int cs = blockIdx.x * CH;
    int ce = min(cs + CH, E);
    for (int ts = cs; ts < ce; ts += TPT) {
        int tcnt = min(TPT, ce - ts);
        // zero histograms (MAXB == TBP: one bucket per thread)
        #pragma unroll
        for (int ww = 0; ww < NW; ww++) { woff[ww][t] = 0u; cnt2[ww][t] = 0u; }
        __syncthreads();
        unsigned es[KPT], ed[KPT]; int nk = 0;
        #pragma unroll
        for (int k = 0; k < KPT; k++) {
            int j = ts + t + k * TBP;
            if (j < ce) {
                es[k] = (unsigned)src[j];
                ed[k] = (unsigned)dst[j];
                atomicAdd(&woff[w][ed[k] >> SB_BITS], 1u);
                nk = k + 1;
            }
        }
        __syncthreads();
        // per-bucket totals -> wave offsets, global cursor, block-wide scan
        unsigned h0 = woff[0][t], h1 = woff[1][t], h2 = woff[2][t], h3 = woff[3][t];
        woff[0][t] = 0u; woff[1][t] = h0; woff[2][t] = h0 + h1;
        woff[3][t] = h0 + h1 + h2;
        unsigned th = h0 + h1 + h2 + h3;
        gbase[t] = th ? atomicAdd(&gcur[(t * NSET + set) * GSTRIDE], th) : 0u;
        unsigned v = th;
        #pragma unroll
        for (int off = 1; off < 64; off <<= 1) {
            unsigned u = __shfl_up(v, off, 64);
            if (lane >= off) v += u;
        }
        if (lane == 63) wtot[w] = v;
        __syncthreads();
        unsigned wpre = 0;
        #pragma unroll
        for (int ww = 0; ww < NW; ww++) wpre += (ww < w) ? wtot[ww] : 0u;
        scn[t] = wpre + v - th;        // block-exclusive base for bucket t
        __syncthreads();
        for (int k = 0; k < nk; k++) {
            unsigned b = ed[k] >> SB_BITS;
            unsigned r = scn[b] + woff[w][b] + atomicAdd(&cnt2[w][b], 1u);
            sp[r]  = es[k] | ((ed[k] & (SBK - 1u)) << 17);
            sbk[r] = (unsigned char)b;
        }
        __syncthreads();
        #pragma unroll
        for (int k = 0; k < KPT; k++) {
            int j2 = t + k * TBP;
            if (j2 < tcnt) {
                unsigned b = sbk[j2];
                unsigned gpos = gbase[b] + (unsigned)j2 - scn[b];
                if (gpos < (unsigned)capS)
                    packedB[(size_t)b * cap + (size_t)set * capS + gpos] = sp[j2];
            }
        }
        __syncthreads();
    }
}

// ---------------- K2: degree (wave-per-set) + prep1 (dis, y) ----------------
__global__ __launch_bounds__(TBA) void degp_k(
        const unsigned* __restrict__ packedB, const unsigned* __restrict__ gcur,
        int cap, int capS, const float* __restrict__ x, int N,
        float* __restrict__ dis, float* __restrict__ y) {
    __shared__ unsigned acc[SBK];
    if (threadIdx.x < SBK) acc[threadIdx.x] = 0u;
    __syncthreads();
    const int b = blockIdx.x;
    const int w = threadIdx.x >> 6;      // wave = set
    const int lane = threadIdx.x & 63;
    unsigned cnt = min(gcur[(b * NSET + w) * GSTRIDE], (unsigned)capS);
    const unsigned* p = packedB + (size_t)b * cap + (size_t)w * capS;
    const uint4* p4 = (const uint4*)p;
    unsigned nq = cnt >> 2;
    unsigned qi = lane;
    for (; qi + 64 < nq; qi += 128) {
        uint4 a = p4[qi], c = p4[qi + 64];
        atomicAdd(&acc[a.x >> 17], 1u); atomicAdd(&acc[a.y >> 17], 1u);
        atomicAdd(&acc[a.z >> 17], 1u); atomicAdd(&acc[a.w >> 17], 1u);
        atomicAdd(&acc[c.x >> 17], 1u); atomicAdd(&acc[c.y >> 17], 1u);
        atomicAdd(&acc[c.z >> 17], 1u); atomicAdd(&acc[c.w >> 17], 1u);
    }
    for (; qi < nq; qi += 64) {
        uint4 a = p4[qi];
        atomicAdd(&acc[a.x >> 17], 1u); atomicAdd(&acc[a.y >> 17], 1u);
        atomicAdd(&acc[a.z >> 17], 1u); atomicAdd(&acc[a.w >> 17], 1u);
    }
    for (unsigned j = (nq << 2) + lane; j < cnt; j += 64)
        atomicAdd(&acc[p[j] >> 17], 1u);
    __syncthreads();
    const int base = b << SB_BITS;
    if (threadIdx.x < SBK) {
        int gi = base + threadIdx.x;
        if (gi < N) {
            float rr = 1.0f / sqrtf((float)(1u + acc[threadIdx.x]));  // +1 self loop
            dis[gi] = rr;
            y[gi] = x[gi] * rr;
        }
    }
}

// ---------------- K3: gather y (wave-per-set) + prep2 (z) ----------------
__global__ __launch_bounds__(TBA) void gacc1_k(
        const unsigned* __restrict__ packedB, const unsigned* __restrict__ gcur,
        const float* __restrict__ val /* y */, int cap, int capS,
        const float* __restrict__ dis,
        const float* __restrict__ W1, const float* __restrict__ b1,
        const float* __restrict__ W2, float* __restrict__ z, int N) {
    __shared__ float acc[SBK];
    __shared__ float sW1[256], sb1[256], sW2[256];
    if (threadIdx.x < 256) {
        sW1[threadIdx.x] = W1[threadIdx.x];
        sb1[threadIdx.x] = b1[threadIdx.x];
        sW2[threadIdx.x] = W2[threadIdx.x];
    }
    if (threadIdx.x < SBK) acc[threadIdx.x] = 0.0f;
    __syncthreads();
    const int b = blockIdx.x;
    const int w = threadIdx.x >> 6;
    const int lane = threadIdx.x & 63;
    unsigned cnt = min(gcur[(b * NSET + w) * GSTRIDE], (unsigned)capS);
    const unsigned* p = packedB + (size_t)b * cap + (size_t)w * capS;
    const uint4* p4 = (const uint4*)p;
    unsigned nq = cnt >> 2;
    unsigned qi = lane;
    for (; qi + 64 < nq; qi += 128) {
        uint4 a = p4[qi], c = p4[qi + 64];
        float v0 = val[a.x & 0x1FFFFu], v1 = val[a.y & 0x1FFFFu];
        float v2 = val[a.z & 0x1FFFFu], v3 = val[a.w & 0x1FFFFu];
        float v4 = val[c.x & 0x1FFFFu], v5 = val[c.y & 0x1FFFFu];
        float v6 = val[c.z & 0x1FFFFu], v7 = val[c.w & 0x1FFFFu];
        lds_addf(&acc[a.x >> 17], v0); lds_addf(&acc[a.y >> 17], v1);
        lds_addf(&acc[a.z >> 17], v2); lds_addf(&acc[a.w >> 17], v3);
        lds_addf(&acc[c.x >> 17], v4); lds_addf(&acc[c.y >> 17], v5);
        lds_addf(&acc[c.z >> 17], v6); lds_addf(&acc[c.w >> 17], v7);
    }
    for (; qi < nq; qi += 64) {
        uint4 a = p4[qi];
        float v0 = val[a.x & 0x1FFFFu], v1 = val[a.y & 0x1FFFFu];
        float v2 = val[a.z & 0x1FFFFu], v3 = val[a.w & 0x1FFFFu];
        lds_addf(&acc[a.x >> 17], v0); lds_addf(&acc[a.y >> 17], v1);
        lds_addf(&acc[a.z >> 17], v2); lds_addf(&acc[a.w >> 17], v3);
    }
    for (unsigned j = (nq << 2) + lane; j < cnt; j += 64) {
        unsigned pk = p[j];
        lds_addf(&acc[pk >> 17], val[pk & 0x1FFFFu]);
    }
    __syncthreads();
    const int base = b << SB_BITS;
    const float4* w1v = (const float4*)sW1;
    const float4* b1v = (const float4*)sb1;
    const float4* w2v = (const float4*)sW2;
    if (threadIdx.x < SBK) {
        int gi = base + threadIdx.x;
        if (gi < N) {
            float tt = acc[threadIdx.x];
            float rr = dis[gi];
            float s = rr * (tt + val[gi]);
            float g = 0.0f;
            #pragma unroll 8
            for (int jj = 0; jj < 64; jj++) {   // H=256 -> 64 quads
                float4 a = w1v[jj], bb = b1v[jj], c = w2v[jj];
                float h0 = fmaf(s, a.x, bb.x); h0 = h0 > 0.0f ? h0 : 0.0f;
                float h1 = fmaf(s, a.y, bb.y); h1 = h1 > 0.0f ? h1 : 0.0f;
                float h2 = fmaf(s, a.z, bb.z); h2 = h2 > 0.0f ? h2 : 0.0f;
                float h3 = fmaf(s, a.w, bb.w); h3 = h3 > 0.0f ? h3 : 0.0f;
                g = fmaf(h0, c.x, g); g = fmaf(h1, c.y, g);
                g = fmaf(h2, c.z, g); g = fmaf(h3, c.w, g);
            }
            z[gi] = g * rr;
        }
    }
}

// ---------------- K4: gather z (wave-per-set) + finout ----------------
__global__ __launch_bounds__(TBA) void gacc2_k(
        const unsigned* __restrict__ packedB, const unsigned* __restrict__ gcur,
        const float* __restrict__ val /* z */, int cap, int capS,
        const float* __restrict__ dis, const float* __restrict__ b2,
        float* __restrict__ out, int N) {
    __shared__ float acc[SBK];
    if (threadIdx.x < SBK) acc[threadIdx.x] = 0.0f;
    __syncthreads();
    const int b = blockIdx.x;
    const int w = threadIdx.x >> 6;
    const int lane = threadIdx.x & 63;
    unsigned cnt = min(gcur[(b * NSET + w) * GSTRIDE], (unsigned)capS);
    const unsigned* p = packedB + (size_t)b * cap + (size_t)w * capS;
    const uint4* p4 = (const uint4*)p;
    unsigned nq = cnt >> 2;
    unsigned qi = lane;
    for (; qi + 64 < nq; qi += 128) {
        uint4 a = p4[qi], c = p4[qi + 64];
        float v0 = val[a.x & 0x1FFFFu], v1 = val[a.y & 0x1FFFFu];
        float v2 = val[a.z & 0x1FFFFu], v3 = val[a.w & 0x1FFFFu];
        float v4 = val[c.x & 0x1FFFFu], v5 = val[c.y & 0x1FFFFu];
        float v6 = val[c.z & 0x1FFFFu], v7 = val[c.w & 0x1FFFFu];
        lds_addf(&acc[a.x >> 17], v0); lds_addf(&acc[a.y >> 17], v1);
        lds_addf(&acc[a.z >> 17], v2); lds_addf(&acc[a.w >> 17], v3);
        lds_addf(&acc[c.x >> 17], v4); lds_addf(&acc[c.y >> 17], v5);
        lds_addf(&acc[c.z >> 17], v6); lds_addf(&acc[c.w >> 17], v7);
    }
    for (; qi < nq; qi += 64) {
        uint4 a = p4[qi];
        float v0 = val[a.x & 0x1FFFFu], v1 = val[a.y & 0x1FFFFu];
        float v2 = val[a.z & 0x1FFFFu], v3 = val[a.w & 0x1FFFFu];
        lds_addf(&acc[a.x >> 17], v0); lds_addf(&acc[a.y >> 17], v1);
        lds_addf(&acc[a.z >> 17], v2); lds_addf(&acc[a.w >> 17], v3);
    }
    for (unsigned j = (nq << 2) + lane; j < cnt; j += 64) {
        unsigned pk = p[j];
        lds_addf(&acc[pk >> 17], val[pk & 0x1FFFFu]);
    }
    __syncthreads();
    const int base = b << SB_BITS;
    float bb2 = b2[0];
    if (threadIdx.x < SBK) {
        int gi = base + threadIdx.x;
        if (gi < N) {
            out[gi] = dis[gi] * (acc[threadIdx.x] + val[gi]) + bb2;
        }
    }
}

extern "C" void kernel_launch(void* const* d_in, const int* in_sizes, int n_in,
                              void* d_out, int out_size, void* d_ws, size_t ws_size,
                              hipStream_t stream) {
    const float* x   = (const float*)d_in[0];
    const int*   ei  = (const int*)d_in[1];     // int32 (JAX x64-off)
    const float* W1  = (const float*)d_in[2];
    const float* b1  = (const float*)d_in[3];
    const float* W2  = (const float*)d_in[4];
    const float* b2  = (const float*)d_in[5];
    float*       out = (float*)d_out;

    const int N = in_sizes[0];        // 100000
    const int E = in_sizes[1] / 2;    // 3200000

    const int* srcp = ei;
    const int* dstp = ei + E;

    const int NB   = (N + SBK - 1) >> SB_BITS;            // 196
    const int capS = (E / (NB * NSET) + 384 + 7) & ~7;    // ~12 sigma slack
    const int cap  = capS * NSET;
    const int NCUR = NB * NSET * GSTRIDE;                 // 25088 u32

    // workspace (u32 units):
    // [gcur NCUR][dis N][y N][z N][packedB NB*cap]
    unsigned* W    = (unsigned*)d_ws;
    unsigned* gcur = W;
    float*    dis  = (float*)(W + (size_t)NCUR);
    float*    y    = (float*)(W + (size_t)NCUR + (size_t)N);
    float*    z    = (float*)(W + (size_t)NCUR + (size_t)2 * N);
    unsigned* packedB = W + (size_t)NCUR + (size_t)3 * N; // 16B-aligned (N%4==0)

    hipMemsetAsync(gcur, 0, (size_t)NCUR * sizeof(unsigned), stream);

    part_k <<<NAPB, TBP, 0, stream>>>(srcp, dstp, E, cap, capS, gcur, packedB);
    degp_k <<<NB, TBA, 0, stream>>>(packedB, gcur, cap, capS, x, N, dis, y);
    gacc1_k<<<NB, TBA, 0, stream>>>(packedB, gcur, y, cap, capS, dis,
                                    W1, b1, W2, z, N);
    gacc2_k<<<NB, TBA, 0, stream>>>(packedB, gcur, z, cap, capS, dis, b2, out, N);
}